// Round 2
// baseline (4470.963 us; speedup 1.0000x reference)
//
#include <hip/hip_runtime.h>
#include <math.h>

// ---------------------------------------------------------------------------
// C=256, H=W=64, BT=16, b=2, t=8, scales (32,16,8,4). fp32 baseline.
// Workspace layout (float offsets). Peak = 47,906,816 floats = 182.75 MiB.
// x1 lives in d_out; ff1 reuses the atten_res region.
// ---------------------------------------------------------------------------
constexpr long long OFF_WLT  = 0;
constexpr long long OFF_WF1T = 589824;
constexpr long long OFF_WF2T = 1179648;
constexpr long long OFF_AT   = 1769472;                 // atten_res (16,256,64,64)
constexpr long long OFF_QP   = OFF_AT + 16777216;       // per-scale patchified Q (b,N,D)
constexpr long long OFF_KP   = OFF_QP + 4194304;
constexpr long long OFF_VP   = OFF_KP + 4194304;
constexpr long long OFF_SC   = OFF_VP + 4194304;        // scores (b,N,N), max 8.39M
constexpr long long OFF_PART = OFF_SC + 8388608;        // split-K partials (max 4.19M)
constexpr long long OFF_VAL  = OFF_PART + 4194304;      // att@V (b,N,D)
constexpr long long NEED_FLOATS = OFF_VAL + 4194304;    // 47,906,816

// ---------------------------------------------------------------------------
// Weight transform: W (O,C,3,3) -> Wt (C, tap, O) for coalesced LDS staging
// ---------------------------------------------------------------------------
__global__ void transform_w(const float* __restrict__ W, float* __restrict__ Wt) {
    int idx = blockIdx.x * 256 + threadIdx.x;           // 256*256*9 = 589824
    if (idx >= 589824) return;
    int o = idx & 255;
    int tap = (idx >> 8) % 9;
    int c = idx / 2304;
    Wt[idx] = W[((long long)o * 256 + c) * 9 + tap];
}

// ---------------------------------------------------------------------------
// Fused QKV slice GEMM with patchified store.
// Computes out[o=m0+c] = W[o]·xs[n] + bias[o] for a 64-row slice, writing
// result directly as patch tokens (b, Ntok, D), D = 64*ph*pw.
// Tile: M=64 x N=128, BK=16, 256 threads, 4x8 micro-tile.
// grid = (32 n-tiles, 3 mats, 16 images).
// ---------------------------------------------------------------------------
__global__ __launch_bounds__(256) void gemm_qkv_patch(
    const float* __restrict__ xs,
    const float* __restrict__ Wq, const float* __restrict__ bq,
    const float* __restrict__ Wk, const float* __restrict__ bk,
    const float* __restrict__ Wv, const float* __restrict__ bv,
    float* __restrict__ Qp, float* __restrict__ Kp, float* __restrict__ Vp,
    int m0, int lp, int oh, int Ntok, int D)
{
    __shared__ float As[16][68];
    __shared__ float Bs[16][128];
    const int mat = blockIdx.y;
    const float* W  = (mat == 0) ? Wq : (mat == 1) ? Wk : Wv;
    const float* bi = (mat == 0) ? bq : (mat == 1) ? bk : bv;
    float* out      = (mat == 0) ? Qp : (mat == 1) ? Kp : Vp;
    const int n0 = blockIdx.x * 128;
    const int n  = blockIdx.z;
    const float* Xn = xs + (long long)n * 1048576;
    const int tid = threadIdx.x;
    const int tx = tid & 15, ty = tid >> 4;
    const int arow = tid >> 2, akc = (tid & 3) * 4;
    const int brow = tid >> 4, bcol = (tid & 15) * 8;

    float acc[4][8];
#pragma unroll
    for (int i = 0; i < 4; ++i) {
        float bv0 = bi[m0 + ty * 4 + i];
#pragma unroll
        for (int j = 0; j < 8; ++j) acc[i][j] = bv0;
    }

    for (int k0 = 0; k0 < 256; k0 += 16) {
        float4 a4 = *(const float4*)(W + (long long)(m0 + arow) * 256 + k0 + akc);
        const float* p = Xn + (long long)(k0 + brow) * 4096 + n0 + bcol;
        float4 b0 = *(const float4*)p;
        float4 b1 = *(const float4*)(p + 4);
        __syncthreads();
        As[akc + 0][arow] = a4.x; As[akc + 1][arow] = a4.y;
        As[akc + 2][arow] = a4.z; As[akc + 3][arow] = a4.w;
        *(float4*)&Bs[brow][bcol]     = b0;
        *(float4*)&Bs[brow][bcol + 4] = b1;
        __syncthreads();
#pragma unroll
        for (int kk = 0; kk < 16; ++kk) {
            float av[4], bvv[8];
            *(float4*)&av[0]  = *(const float4*)&As[kk][ty * 4];
            *(float4*)&bvv[0] = *(const float4*)&Bs[kk][tx * 8];
            *(float4*)&bvv[4] = *(const float4*)&Bs[kk][tx * 8 + 4];
#pragma unroll
            for (int i = 0; i < 4; ++i)
#pragma unroll
                for (int j = 0; j < 8; ++j)
                    acc[i][j] = fmaf(av[i], bvv[j], acc[i][j]);
        }
    }

    // patchified store: c=channel-in-slice, pixel p -> (token m, elem e)
    const int b2 = n >> 3, tt = n & 7;
    const int pm = (1 << lp) - 1;
#pragma unroll
    for (int i = 0; i < 4; ++i) {
        int c = ty * 4 + i;
#pragma unroll
        for (int jj = 0; jj < 8; jj += 4) {
            int p0 = n0 + tx * 8 + jj;
            int y = p0 >> 6, x = p0 & 63;
            int m = (tt * oh + (y >> lp)) * oh + (x >> lp);
            int e = ((((c << lp) + (y & pm)) << lp) + (x & pm));
            long long dst = ((long long)(b2 * Ntok + m)) * D + e;
            *(float4*)(out + dst) = *(float4*)&acc[i][jj];
        }
    }
}

// ---------------------------------------------------------------------------
// Generic fp32 GEMM (NN): C[m][n] = sum_k A[m][k]*B[k][n]
// Tile 128x128, BK=16, 256 threads, 8x8 micro-tile. Batched via blockIdx.z.
// M may be < tile (guarded); N,K multiples of 128/16.
// ---------------------------------------------------------------------------
__global__ __launch_bounds__(256) void gemm_nn(
    const float* __restrict__ A, const float* __restrict__ B,
    float* __restrict__ C, int M, int N, int K,
    long long sA, long long sB, long long sC)
{
    __shared__ float As[16][132];
    __shared__ float Bs[16][128];
    const int bz = blockIdx.z;
    const float* Ab = A + bz * sA;
    const float* Bb = B + bz * sB;
    float* Cb = C + bz * sC;
    const int n0 = blockIdx.x * 128;
    const int m0 = blockIdx.y * 128;
    const int tid = threadIdx.x;
    const int tx = tid & 15, ty = tid >> 4;
    const int arow = tid >> 1, ak = (tid & 1) * 8;
    const int brow = tid >> 4, bcol = (tid & 15) * 8;

    float acc[8][8];
#pragma unroll
    for (int i = 0; i < 8; ++i)
#pragma unroll
        for (int j = 0; j < 8; ++j) acc[i][j] = 0.f;

    for (int k0 = 0; k0 < K; k0 += 16) {
        float4 a0, a1, b0, b1;
        {
            int r = m0 + arow;
            if (r < M) {
                const float* p = Ab + (long long)r * K + (k0 + ak);
                a0 = *(const float4*)p;
                a1 = *(const float4*)(p + 4);
            } else {
                a0 = make_float4(0.f, 0.f, 0.f, 0.f); a1 = a0;
            }
        }
        {
            const float* p = Bb + (long long)(k0 + brow) * N + (n0 + bcol);
            b0 = *(const float4*)p;
            b1 = *(const float4*)(p + 4);
        }
        __syncthreads();
        As[ak + 0][arow] = a0.x; As[ak + 1][arow] = a0.y;
        As[ak + 2][arow] = a0.z; As[ak + 3][arow] = a0.w;
        As[ak + 4][arow] = a1.x; As[ak + 5][arow] = a1.y;
        As[ak + 6][arow] = a1.z; As[ak + 7][arow] = a1.w;
        *(float4*)&Bs[brow][bcol]     = b0;
        *(float4*)&Bs[brow][bcol + 4] = b1;
        __syncthreads();
#pragma unroll
        for (int kk = 0; kk < 16; ++kk) {
            float av[8], bv[8];
            *(float4*)&av[0] = *(const float4*)&As[kk][ty * 8];
            *(float4*)&av[4] = *(const float4*)&As[kk][ty * 8 + 4];
            *(float4*)&bv[0] = *(const float4*)&Bs[kk][tx * 8];
            *(float4*)&bv[4] = *(const float4*)&Bs[kk][tx * 8 + 4];
#pragma unroll
            for (int i = 0; i < 8; ++i)
#pragma unroll
                for (int j = 0; j < 8; ++j)
                    acc[i][j] = fmaf(av[i], bv[j], acc[i][j]);
        }
    }
#pragma unroll
    for (int i = 0; i < 8; ++i) {
        int r = m0 + ty * 8 + i;
        if (r < M) {
            float* p = Cb + (long long)r * N + n0 + tx * 8;
            *(float4*)p       = *(float4*)&acc[i][0];
            *(float4*)(p + 4) = *(float4*)&acc[i][4];
        }
    }
}

// ---------------------------------------------------------------------------
// Split-K NT GEMM for scores: P[(s*2+b)] [i][j] = sum_{k-slice s} Q_i . K_j
// ---------------------------------------------------------------------------
__global__ __launch_bounds__(256) void gemm_nt_splitk(
    const float* __restrict__ Qp, const float* __restrict__ Kp,
    float* __restrict__ P, int Ntok, int D, int S)
{
    __shared__ float As[16][132];
    __shared__ float Bs[16][132];
    const int j0 = blockIdx.x * 128, i0 = blockIdx.y * 128;
    const int bz = blockIdx.z;
    const int b = bz / S, s = bz % S;
    const int klen = D / S;
    const long long kbeg = (long long)s * klen;
    const float* Ab = Qp + (long long)b * Ntok * D;
    const float* Bb = Kp + (long long)b * Ntok * D;
    const int tid = threadIdx.x;
    const int tx = tid & 15, ty = tid >> 4;
    const int arow = tid >> 1, ak = (tid & 1) * 8;

    float acc[8][8];
#pragma unroll
    for (int i = 0; i < 8; ++i)
#pragma unroll
        for (int j = 0; j < 8; ++j) acc[i][j] = 0.f;

    for (int kc = 0; kc < klen; kc += 16) {
        const long long kk0 = kbeg + kc;
        float4 a0, a1, b0, b1;
        {
            int r = i0 + arow;
            if (r < Ntok) {
                const float* p = Ab + (long long)r * D + kk0 + ak;
                a0 = *(const float4*)p; a1 = *(const float4*)(p + 4);
            } else { a0 = make_float4(0.f,0.f,0.f,0.f); a1 = a0; }
        }
        {
            int r = j0 + arow;
            if (r < Ntok) {
                const float* p = Bb + (long long)r * D + kk0 + ak;
                b0 = *(const float4*)p; b1 = *(const float4*)(p + 4);
            } else { b0 = make_float4(0.f,0.f,0.f,0.f); b1 = b0; }
        }
        __syncthreads();
        As[ak + 0][arow] = a0.x; As[ak + 1][arow] = a0.y;
        As[ak + 2][arow] = a0.z; As[ak + 3][arow] = a0.w;
        As[ak + 4][arow] = a1.x; As[ak + 5][arow] = a1.y;
        As[ak + 6][arow] = a1.z; As[ak + 7][arow] = a1.w;
        Bs[ak + 0][arow] = b0.x; Bs[ak + 1][arow] = b0.y;
        Bs[ak + 2][arow] = b0.z; Bs[ak + 3][arow] = b0.w;
        Bs[ak + 4][arow] = b1.x; Bs[ak + 5][arow] = b1.y;
        Bs[ak + 6][arow] = b1.z; Bs[ak + 7][arow] = b1.w;
        __syncthreads();
#pragma unroll
        for (int kk = 0; kk < 16; ++kk) {
            float av[8], bv[8];
            *(float4*)&av[0] = *(const float4*)&As[kk][ty * 8];
            *(float4*)&av[4] = *(const float4*)&As[kk][ty * 8 + 4];
            *(float4*)&bv[0] = *(const float4*)&Bs[kk][tx * 8];
            *(float4*)&bv[4] = *(const float4*)&Bs[kk][tx * 8 + 4];
#pragma unroll
            for (int i = 0; i < 8; ++i)
#pragma unroll
                for (int j = 0; j < 8; ++j)
                    acc[i][j] = fmaf(av[i], bv[j], acc[i][j]);
        }
    }
    float* Pb = P + ((long long)(s * 2 + b) * Ntok) * Ntok;
#pragma unroll
    for (int i = 0; i < 8; ++i) {
        int r = i0 + ty * 8 + i;
        if (r < Ntok) {
            int cb = j0 + tx * 8;
            if (cb < Ntok) {
                float* p = Pb + (long long)r * Ntok + cb;
                *(float4*)p       = *(float4*)&acc[i][0];
                *(float4*)(p + 4) = *(float4*)&acc[i][4];
            }
        }
    }
}

// sum split-K partials and apply 1/sqrt(D). Alias-safe when Sc==P && S==1.
__global__ void reduce_scale(const float* __restrict__ P, float* __restrict__ Sc,
                             int Ntok, int S, float inv) {
    long long idx = (long long)blockIdx.x * 256 + threadIdx.x;
    long long tot = 2LL * Ntok * Ntok;
    if (idx >= tot) return;
    float a = 0.f;
    for (int s = 0; s < S; ++s) a += P[(long long)s * tot + idx];
    Sc[idx] = a * inv;
}

// row softmax, in place. grid = 2*Ntok rows, 256 threads.
__global__ __launch_bounds__(256) void softmax_rows(float* __restrict__ Sc, int Ntok) {
    float* p = Sc + (long long)blockIdx.x * Ntok;
    const int tid = threadIdx.x;
    const int lane = tid & 63, wv = tid >> 6;
    __shared__ float redm[4];
    __shared__ float reds[4];

    float m = -3.402823466e38f;
    for (int j = tid; j < Ntok; j += 256) m = fmaxf(m, p[j]);
#pragma unroll
    for (int o = 1; o < 64; o <<= 1) m = fmaxf(m, __shfl_xor(m, o, 64));
    if (lane == 0) redm[wv] = m;
    __syncthreads();
    m = fmaxf(fmaxf(redm[0], redm[1]), fmaxf(redm[2], redm[3]));

    float sum = 0.f;
    for (int j = tid; j < Ntok; j += 256) {
        float e = expf(p[j] - m);
        p[j] = e;
        sum += e;
    }
#pragma unroll
    for (int o = 1; o < 64; o <<= 1) sum += __shfl_xor(sum, o, 64);
    if (lane == 0) reds[wv] = sum;
    __syncthreads();
    sum = reds[0] + reds[1] + reds[2] + reds[3];
    float inv = 1.f / sum;
    for (int j = tid; j < Ntok; j += 256) p[j] *= inv;
}

// un-patchify: val (b,N,D) -> atten_res channel slice (bt, 64ch, h, w)
__global__ void unpatchify(const float* __restrict__ val, float* __restrict__ at,
                           int off, int ph, int pw, int oh, int ow, int Ntok, int D) {
    unsigned idx = blockIdx.x * 256 + threadIdx.x;   // over 16*64*4096 = 4194304
    if (idx >= 4194304u) return;
    unsigned x = idx & 63u, y = (idx >> 6) & 63u, c = (idx >> 12) & 63u;
    unsigned img = idx >> 18;
    unsigned b = img >> 3, tt = img & 7u;
    unsigned ohh = y / (unsigned)ph, phh = y % (unsigned)ph;
    unsigned oww = x / (unsigned)pw, pww = x % (unsigned)pw;
    unsigned mtk = (tt * oh + ohh) * ow + oww;
    unsigned e = (c * ph + phh) * pw + pww;
    at[(((long long)img * 256 + off + c) << 12) + (y << 6) + x] =
        val[((long long)b * Ntok + mtk) * D + e];
}

// ---------------------------------------------------------------------------
// Direct 3x3 conv (opt. dilated), fused leaky-relu + optional residual add.
// Block: 64 oc x 4 rows x 64 cols; K-loop over 256 in chunks of 8.
// ---------------------------------------------------------------------------
template <int DIL, bool HAS_RES>
__global__ __launch_bounds__(256) void conv3x3_k(
    const float* __restrict__ X, const float* __restrict__ Wt,
    const float* __restrict__ bias, const float* __restrict__ res,
    float* __restrict__ out)
{
    constexpr int RW = 64 + 2 * DIL;
    constexpr int RH = 4 + 2 * DIL;
    const int y0 = blockIdx.x * 4;
    const int o0 = blockIdx.y * 64;
    const int n = blockIdx.z;
    __shared__ float xt[8][RH][RW];
    __shared__ float wt[8][9][64];
    const int tid = threadIdx.x;
    const int tx = tid & 15, to = tid >> 4;

    float acc[4][4][4];   // [oo][yy][xx]
#pragma unroll
    for (int oo = 0; oo < 4; ++oo) {
        float bv = bias[o0 + to * 4 + oo];
#pragma unroll
        for (int yy = 0; yy < 4; ++yy)
#pragma unroll
            for (int xx = 0; xx < 4; ++xx) acc[oo][yy][xx] = bv;
    }

    const float* Xn = X + (long long)n * 1048576;

    for (int c0 = 0; c0 < 256; c0 += 8) {
        constexpr int XT = 8 * RH * RW;
        for (int l = tid; l < XT; l += 256) {
            int col = l % RW;
            int r = (l / RW) % RH;
            int cc = l / (RW * RH);
            int yg = y0 + r - DIL;
            int xg = col - DIL;
            float vv = 0.f;
            if (yg >= 0 && yg < 64 && xg >= 0 && xg < 64)
                vv = Xn[((long long)(c0 + cc) << 12) + (yg << 6) + xg];
            xt[cc][r][col] = vv;
        }
        for (int l = tid; l < 8 * 9 * 64; l += 256) {
            int o = l & 63;
            int tap = (l >> 6) % 9;
            int cc = l / 576;
            wt[cc][tap][o] = Wt[((long long)(c0 + cc) * 9 + tap) * 256 + o0 + o];
        }
        __syncthreads();
#pragma unroll
        for (int cc = 0; cc < 8; ++cc) {
#pragma unroll
            for (int dy = 0; dy < 3; ++dy) {
                float wv[3][4];
#pragma unroll
                for (int dx = 0; dx < 3; ++dx)
#pragma unroll
                    for (int oo = 0; oo < 4; ++oo)
                        wv[dx][oo] = wt[cc][dy * 3 + dx][to * 4 + oo];
#pragma unroll
                for (int yy = 0; yy < 4; ++yy) {
                    float v[4 + 2 * DIL];
#pragma unroll
                    for (int j = 0; j < 4 + 2 * DIL; ++j)
                        v[j] = xt[cc][yy + dy * DIL][tx * 4 + j];
#pragma unroll
                    for (int xx = 0; xx < 4; ++xx)
#pragma unroll
                        for (int dx = 0; dx < 3; ++dx)
#pragma unroll
                            for (int oo = 0; oo < 4; ++oo)
                                acc[oo][yy][xx] =
                                    fmaf(wv[dx][oo], v[xx + dx * DIL], acc[oo][yy][xx]);
                }
            }
        }
        __syncthreads();
    }
#pragma unroll
    for (int oo = 0; oo < 4; ++oo) {
        int o = o0 + to * 4 + oo;
#pragma unroll
        for (int yy = 0; yy < 4; ++yy) {
            long long base = (((long long)n * 256 + o) << 12) + ((long long)(y0 + yy) << 6) + tx * 4;
            float4 r4;
#pragma unroll
            for (int xx = 0; xx < 4; ++xx) {
                float a = acc[oo][yy][xx];
                a = a > 0.f ? a : 0.2f * a;
                ((float*)&r4)[xx] = a;
            }
            if (HAS_RES) {
                float4 rr = *(const float4*)(res + base);   // same-thread same-addr as store
                r4.x += rr.x; r4.y += rr.y; r4.z += rr.z; r4.w += rr.w;
            }
            *(float4*)(out + base) = r4;
        }
    }
}

// ---------------------------------------------------------------------------
extern "C" void kernel_launch(void* const* d_in, const int* in_sizes, int n_in,
                              void* d_out, int out_size, void* d_ws, size_t ws_size,
                              hipStream_t stream)
{
    // Diagnostic guard: if ws is too small, do nothing -> clean absmax fail,
    // not a memory-fault core dump. (NEED = 182.75 MiB)
    if (ws_size < (size_t)NEED_FLOATS * sizeof(float)) return;

    const float* xs  = (const float*)d_in[0];
    // d_in[1] = ms : dead in the reference (masked_fill result discarded)
    const float* Wq  = (const float*)d_in[2];
    const float* bq  = (const float*)d_in[3];
    const float* Wk  = (const float*)d_in[4];
    const float* bk  = (const float*)d_in[5];
    const float* Wv  = (const float*)d_in[6];
    const float* bv  = (const float*)d_in[7];
    const float* Wl  = (const float*)d_in[8];
    const float* bl  = (const float*)d_in[9];
    const float* Wf1 = (const float*)d_in[10];
    const float* bf1 = (const float*)d_in[11];
    const float* Wf2 = (const float*)d_in[12];
    const float* bf2 = (const float*)d_in[13];

    float* ws   = (float*)d_ws;
    float* wlt  = ws + OFF_WLT;
    float* wf1t = ws + OFF_WF1T;
    float* wf2t = ws + OFF_WF2T;
    float* at   = ws + OFF_AT;
    float* Qp   = ws + OFF_QP;
    float* Kp   = ws + OFF_KP;
    float* Vp   = ws + OFF_VP;
    float* sc   = ws + OFF_SC;
    float* part = ws + OFF_PART;
    float* val  = ws + OFF_VAL;
    float* x1   = (float*)d_out;    // x1 lives in d_out (conv3 res is same-addr)
    float* ff1  = at;               // atten_res dead after conv1

    // 1) weight transforms (tiny)
    transform_w<<<2304, 256, 0, stream>>>(Wl, wlt);
    transform_w<<<2304, 256, 0, stream>>>(Wf1, wf1t);
    transform_w<<<2304, 256, 0, stream>>>(Wf2, wf2t);

    // 2) per-scale attention (QKV slice GEMM fused with patchify)
    const int PH[4]  = {32, 16, 8, 4};
    const int LP[4]  = {5, 4, 3, 2};
    const int SPL[4] = {256, 128, 8, 1};   // split-K (klen multiple of 16)
    for (int i = 0; i < 4; ++i) {
        const int ph = PH[i], lp = LP[i];
        const int oh = 64 / ph;
        const int Ntok = 8 * oh * oh;
        const int D = 64 * ph * ph;
        const int off = i * 64;
        const int S = SPL[i];

        {   // q/k/v 64-ch slice -> patch tokens
            dim3 g(32, 3, 16);
            gemm_qkv_patch<<<g, 256, 0, stream>>>(xs, Wq, bq, Wk, bk, Wv, bv,
                                                  Qp, Kp, Vp, off, lp, oh, Ntok, D);
        }

        const int nt = (Ntok + 127) / 128;
        float* pbuf = (S == 1) ? sc : part;
        {   // scores = Q K^T (split-K)
            dim3 g1(nt, nt, 2 * S);
            gemm_nt_splitk<<<g1, 256, 0, stream>>>(Qp, Kp, pbuf, Ntok, D, S);
        }
        const long long nn2 = 2LL * Ntok * Ntok;
        const float inv = 1.0f / sqrtf((float)D);
        reduce_scale<<<(int)((nn2 + 255) / 256), 256, 0, stream>>>(pbuf, sc, Ntok, S, inv);

        softmax_rows<<<2 * Ntok, 256, 0, stream>>>(sc, Ntok);

        {   // val = att @ V
            dim3 g2(D / 128, nt, 2);
            gemm_nn<<<g2, 256, 0, stream>>>(sc, Vp, val, Ntok, D, Ntok,
                                            (long long)Ntok * Ntok,
                                            (long long)Ntok * D,
                                            (long long)Ntok * D);
        }

        unpatchify<<<16384, 256, 0, stream>>>(val, at, off, ph, ph, oh, oh, Ntok, D);
    }

    // 3) conv chain
    dim3 gc(16, 4, 16);
    conv3x3_k<1, true ><<<gc, 256, 0, stream>>>(at,  wlt,  bl,  xs,      x1);  // x1 = xs + leaky(conv)
    conv3x3_k<1, false><<<gc, 256, 0, stream>>>(x1,  wf1t, bf1, nullptr, ff1); // ff1 = leaky(conv)
    conv3x3_k<2, true ><<<gc, 256, 0, stream>>>(ff1, wf2t, bf2, x1, (float*)d_out); // out = x1 + leaky(dconv)
}

// Round 3
// 1872.137 us; speedup vs baseline: 2.3882x; 2.3882x over previous
//
#include <hip/hip_runtime.h>
#include <hip/hip_bf16.h>
#include <math.h>

// ---------------------------------------------------------------------------
// C=256, H=W=64, BT=16, b=2, t=8, scales (32,16,8,4).
// This round: conv chain -> bf16 MFMA (fp32 accum); attention stays fp32.
// Workspace peak = 47,022,080 floats = 179.4 MiB (< proven-working 182.75).
// ---------------------------------------------------------------------------
typedef __attribute__((ext_vector_type(8))) short short8;
typedef __attribute__((ext_vector_type(4))) float f32x4;

constexpr long long OFF_WTB0 = 0;          // 3x 589824 bf16 = 294912 floats each
constexpr long long OFF_WTB1 = 294912;
constexpr long long OFF_WTB2 = 589824;
constexpr long long OFF_AT   = 884736;     // atten_res fp32 chw (16,256,64,64)
constexpr long long OFF_SCR  = 17661952;   // attention scratch region
constexpr long long SCR_QP   = 0;          // 4194304
constexpr long long SCR_KP   = 4194304;
constexpr long long SCR_VP   = 8388608;
constexpr long long SCR_SC   = 12582912;   // 8388608
constexpr long long SCR_PART = 20971520;   // 4194304
constexpr long long SCR_VAL  = 25165824;   // 4194304
constexpr long long NEED_FLOATS = OFF_SCR + 29360128;  // 47,022,080
// aliases into SCR after attention is done (buffers dead):
//   atb  (bf16, 16.7M elems = 8388608 float-slots) at SCR+0
//   x1b  (bf16) at SCR+8388608
//   ff1b (bf16) at SCR+16777216

// ---------------------------------------------------------------------------
// Wq/Wl-style 3x3 weight transform -> bf16 MFMA layout
// Wtb[chunk(8)][tap(9)][khi(4)][oc(256)][ic8(8)], c = chunk*32+khi*8+i
// ---------------------------------------------------------------------------
__global__ void transform_w_bf(const float* __restrict__ W, __hip_bfloat16* __restrict__ Wt) {
    int idx = blockIdx.x * 256 + threadIdx.x;      // 589824
    if (idx >= 589824) return;
    int i    = idx & 7;
    int o    = (idx >> 3) & 255;
    int khi  = (idx >> 11) & 3;
    int tap  = (idx >> 13) % 9;
    int chunk = idx / 73728;
    int c = chunk * 32 + khi * 8 + i;
    Wt[idx] = __float2bfloat16(W[((long long)o * 256 + c) * 9 + tap]);
}

// ---------------------------------------------------------------------------
// Fused QKV slice GEMM with patchified store (fp32, unchanged from baseline)
// ---------------------------------------------------------------------------
__global__ __launch_bounds__(256) void gemm_qkv_patch(
    const float* __restrict__ xs,
    const float* __restrict__ Wq, const float* __restrict__ bq,
    const float* __restrict__ Wk, const float* __restrict__ bk,
    const float* __restrict__ Wv, const float* __restrict__ bv,
    float* __restrict__ Qp, float* __restrict__ Kp, float* __restrict__ Vp,
    int m0, int lp, int oh, int Ntok, int D)
{
    __shared__ float As[16][68];
    __shared__ float Bs[16][128];
    const int mat = blockIdx.y;
    const float* W  = (mat == 0) ? Wq : (mat == 1) ? Wk : Wv;
    const float* bi = (mat == 0) ? bq : (mat == 1) ? bk : bv;
    float* out      = (mat == 0) ? Qp : (mat == 1) ? Kp : Vp;
    const int n0 = blockIdx.x * 128;
    const int n  = blockIdx.z;
    const float* Xn = xs + (long long)n * 1048576;
    const int tid = threadIdx.x;
    const int tx = tid & 15, ty = tid >> 4;
    const int arow = tid >> 2, akc = (tid & 3) * 4;
    const int brow = tid >> 4, bcol = (tid & 15) * 8;

    float acc[4][8];
#pragma unroll
    for (int i = 0; i < 4; ++i) {
        float bv0 = bi[m0 + ty * 4 + i];
#pragma unroll
        for (int j = 0; j < 8; ++j) acc[i][j] = bv0;
    }

    for (int k0 = 0; k0 < 256; k0 += 16) {
        float4 a4 = *(const float4*)(W + (long long)(m0 + arow) * 256 + k0 + akc);
        const float* p = Xn + (long long)(k0 + brow) * 4096 + n0 + bcol;
        float4 b0 = *(const float4*)p;
        float4 b1 = *(const float4*)(p + 4);
        __syncthreads();
        As[akc + 0][arow] = a4.x; As[akc + 1][arow] = a4.y;
        As[akc + 2][arow] = a4.z; As[akc + 3][arow] = a4.w;
        *(float4*)&Bs[brow][bcol]     = b0;
        *(float4*)&Bs[brow][bcol + 4] = b1;
        __syncthreads();
#pragma unroll
        for (int kk = 0; kk < 16; ++kk) {
            float av[4], bvv[8];
            *(float4*)&av[0]  = *(const float4*)&As[kk][ty * 4];
            *(float4*)&bvv[0] = *(const float4*)&Bs[kk][tx * 8];
            *(float4*)&bvv[4] = *(const float4*)&Bs[kk][tx * 8 + 4];
#pragma unroll
            for (int i = 0; i < 4; ++i)
#pragma unroll
                for (int j = 0; j < 8; ++j)
                    acc[i][j] = fmaf(av[i], bvv[j], acc[i][j]);
        }
    }

    const int b2 = n >> 3, tt = n & 7;
    const int pm = (1 << lp) - 1;
#pragma unroll
    for (int i = 0; i < 4; ++i) {
        int c = ty * 4 + i;
#pragma unroll
        for (int jj = 0; jj < 8; jj += 4) {
            int p0 = n0 + tx * 8 + jj;
            int y = p0 >> 6, x = p0 & 63;
            int m = (tt * oh + (y >> lp)) * oh + (x >> lp);
            int e = ((((c << lp) + (y & pm)) << lp) + (x & pm));
            long long dst = ((long long)(b2 * Ntok + m)) * D + e;
            *(float4*)(out + dst) = *(float4*)&acc[i][jj];
        }
    }
}

// ---------------------------------------------------------------------------
// fp32 GEMM NN (attention att@V), unchanged
// ---------------------------------------------------------------------------
__global__ __launch_bounds__(256) void gemm_nn(
    const float* __restrict__ A, const float* __restrict__ B,
    float* __restrict__ C, int M, int N, int K,
    long long sA, long long sB, long long sC)
{
    __shared__ float As[16][132];
    __shared__ float Bs[16][128];
    const int bz = blockIdx.z;
    const float* Ab = A + bz * sA;
    const float* Bb = B + bz * sB;
    float* Cb = C + bz * sC;
    const int n0 = blockIdx.x * 128;
    const int m0 = blockIdx.y * 128;
    const int tid = threadIdx.x;
    const int tx = tid & 15, ty = tid >> 4;
    const int arow = tid >> 1, ak = (tid & 1) * 8;
    const int brow = tid >> 4, bcol = (tid & 15) * 8;

    float acc[8][8];
#pragma unroll
    for (int i = 0; i < 8; ++i)
#pragma unroll
        for (int j = 0; j < 8; ++j) acc[i][j] = 0.f;

    for (int k0 = 0; k0 < K; k0 += 16) {
        float4 a0, a1, b0, b1;
        {
            int r = m0 + arow;
            if (r < M) {
                const float* p = Ab + (long long)r * K + (k0 + ak);
                a0 = *(const float4*)p;
                a1 = *(const float4*)(p + 4);
            } else {
                a0 = make_float4(0.f, 0.f, 0.f, 0.f); a1 = a0;
            }
        }
        {
            const float* p = Bb + (long long)(k0 + brow) * N + (n0 + bcol);
            b0 = *(const float4*)p;
            b1 = *(const float4*)(p + 4);
        }
        __syncthreads();
        As[ak + 0][arow] = a0.x; As[ak + 1][arow] = a0.y;
        As[ak + 2][arow] = a0.z; As[ak + 3][arow] = a0.w;
        As[ak + 4][arow] = a1.x; As[ak + 5][arow] = a1.y;
        As[ak + 6][arow] = a1.z; As[ak + 7][arow] = a1.w;
        *(float4*)&Bs[brow][bcol]     = b0;
        *(float4*)&Bs[brow][bcol + 4] = b1;
        __syncthreads();
#pragma unroll
        for (int kk = 0; kk < 16; ++kk) {
            float av[8], bv[8];
            *(float4*)&av[0] = *(const float4*)&As[kk][ty * 8];
            *(float4*)&av[4] = *(const float4*)&As[kk][ty * 8 + 4];
            *(float4*)&bv[0] = *(const float4*)&Bs[kk][tx * 8];
            *(float4*)&bv[4] = *(const float4*)&Bs[kk][tx * 8 + 4];
#pragma unroll
            for (int i = 0; i < 8; ++i)
#pragma unroll
                for (int j = 0; j < 8; ++j)
                    acc[i][j] = fmaf(av[i], bv[j], acc[i][j]);
        }
    }
#pragma unroll
    for (int i = 0; i < 8; ++i) {
        int r = m0 + ty * 8 + i;
        if (r < M) {
            float* p = Cb + (long long)r * N + n0 + tx * 8;
            *(float4*)p       = *(float4*)&acc[i][0];
            *(float4*)(p + 4) = *(float4*)&acc[i][4];
        }
    }
}

// ---------------------------------------------------------------------------
// Split-K NT GEMM for scores (fp32, unchanged)
// ---------------------------------------------------------------------------
__global__ __launch_bounds__(256) void gemm_nt_splitk(
    const float* __restrict__ Qp, const float* __restrict__ Kp,
    float* __restrict__ P, int Ntok, int D, int S)
{
    __shared__ float As[16][132];
    __shared__ float Bs[16][132];
    const int j0 = blockIdx.x * 128, i0 = blockIdx.y * 128;
    const int bz = blockIdx.z;
    const int b = bz / S, s = bz % S;
    const int klen = D / S;
    const long long kbeg = (long long)s * klen;
    const float* Ab = Qp + (long long)b * Ntok * D;
    const float* Bb = Kp + (long long)b * Ntok * D;
    const int tid = threadIdx.x;
    const int tx = tid & 15, ty = tid >> 4;
    const int arow = tid >> 1, ak = (tid & 1) * 8;

    float acc[8][8];
#pragma unroll
    for (int i = 0; i < 8; ++i)
#pragma unroll
        for (int j = 0; j < 8; ++j) acc[i][j] = 0.f;

    for (int kc = 0; kc < klen; kc += 16) {
        const long long kk0 = kbeg + kc;
        float4 a0, a1, b0, b1;
        {
            int r = i0 + arow;
            if (r < Ntok) {
                const float* p = Ab + (long long)r * D + kk0 + ak;
                a0 = *(const float4*)p; a1 = *(const float4*)(p + 4);
            } else { a0 = make_float4(0.f,0.f,0.f,0.f); a1 = a0; }
        }
        {
            int r = j0 + arow;
            if (r < Ntok) {
                const float* p = Bb + (long long)r * D + kk0 + ak;
                b0 = *(const float4*)p; b1 = *(const float4*)(p + 4);
            } else { b0 = make_float4(0.f,0.f,0.f,0.f); b1 = b0; }
        }
        __syncthreads();
        As[ak + 0][arow] = a0.x; As[ak + 1][arow] = a0.y;
        As[ak + 2][arow] = a0.z; As[ak + 3][arow] = a0.w;
        As[ak + 4][arow] = a1.x; As[ak + 5][arow] = a1.y;
        As[ak + 6][arow] = a1.z; As[ak + 7][arow] = a1.w;
        Bs[ak + 0][arow] = b0.x; Bs[ak + 1][arow] = b0.y;
        Bs[ak + 2][arow] = b0.z; Bs[ak + 3][arow] = b0.w;
        Bs[ak + 4][arow] = b1.x; Bs[ak + 5][arow] = b1.y;
        Bs[ak + 6][arow] = b1.z; Bs[ak + 7][arow] = b1.w;
        __syncthreads();
#pragma unroll
        for (int kk = 0; kk < 16; ++kk) {
            float av[8], bv[8];
            *(float4*)&av[0] = *(const float4*)&As[kk][ty * 8];
            *(float4*)&av[4] = *(const float4*)&As[kk][ty * 8 + 4];
            *(float4*)&bv[0] = *(const float4*)&Bs[kk][tx * 8];
            *(float4*)&bv[4] = *(const float4*)&Bs[kk][tx * 8 + 4];
#pragma unroll
            for (int i = 0; i < 8; ++i)
#pragma unroll
                for (int j = 0; j < 8; ++j)
                    acc[i][j] = fmaf(av[i], bv[j], acc[i][j]);
        }
    }
    float* Pb = P + ((long long)(s * 2 + b) * Ntok) * Ntok;
#pragma unroll
    for (int i = 0; i < 8; ++i) {
        int r = i0 + ty * 8 + i;
        if (r < Ntok) {
            int cb = j0 + tx * 8;
            if (cb < Ntok) {
                float* p = Pb + (long long)r * Ntok + cb;
                *(float4*)p       = *(float4*)&acc[i][0];
                *(float4*)(p + 4) = *(float4*)&acc[i][4];
            }
        }
    }
}

__global__ void reduce_scale(const float* __restrict__ P, float* __restrict__ Sc,
                             int Ntok, int S, float inv) {
    long long idx = (long long)blockIdx.x * 256 + threadIdx.x;
    long long tot = 2LL * Ntok * Ntok;
    if (idx >= tot) return;
    float a = 0.f;
    for (int s = 0; s < S; ++s) a += P[(long long)s * tot + idx];
    Sc[idx] = a * inv;
}

__global__ __launch_bounds__(256) void softmax_rows(float* __restrict__ Sc, int Ntok) {
    float* p = Sc + (long long)blockIdx.x * Ntok;
    const int tid = threadIdx.x;
    const int lane = tid & 63, wv = tid >> 6;
    __shared__ float redm[4];
    __shared__ float reds[4];

    float m = -3.402823466e38f;
    for (int j = tid; j < Ntok; j += 256) m = fmaxf(m, p[j]);
#pragma unroll
    for (int o = 1; o < 64; o <<= 1) m = fmaxf(m, __shfl_xor(m, o, 64));
    if (lane == 0) redm[wv] = m;
    __syncthreads();
    m = fmaxf(fmaxf(redm[0], redm[1]), fmaxf(redm[2], redm[3]));

    float sum = 0.f;
    for (int j = tid; j < Ntok; j += 256) {
        float e = expf(p[j] - m);
        p[j] = e;
        sum += e;
    }
#pragma unroll
    for (int o = 1; o < 64; o <<= 1) sum += __shfl_xor(sum, o, 64);
    if (lane == 0) reds[wv] = sum;
    __syncthreads();
    sum = reds[0] + reds[1] + reds[2] + reds[3];
    float inv = 1.f / sum;
    for (int j = tid; j < Ntok; j += 256) p[j] *= inv;
}

// un-patchify: val (b,N,D) -> atten_res channel slice, fp32 chw
__global__ void unpatchify(const float* __restrict__ val, float* __restrict__ at,
                           int off, int ph, int pw, int oh, int ow, int Ntok, int D) {
    unsigned idx = blockIdx.x * 256 + threadIdx.x;
    if (idx >= 4194304u) return;
    unsigned x = idx & 63u, y = (idx >> 6) & 63u, c = (idx >> 12) & 63u;
    unsigned img = idx >> 18;
    unsigned b = img >> 3, tt = img & 7u;
    unsigned ohh = y / (unsigned)ph, phh = y % (unsigned)ph;
    unsigned oww = x / (unsigned)pw, pww = x % (unsigned)pw;
    unsigned mtk = (tt * oh + ohh) * ow + oww;
    unsigned e = (c * ph + phh) * pw + pww;
    at[(((long long)img * 256 + off + c) << 12) + (y << 6) + x] =
        val[((long long)b * Ntok + mtk) * D + e];
}

// ---------------------------------------------------------------------------
// Channels-first fp32 -> channels-last bf16. Reads fully coalesced (8 rows),
// one 16B store per thread. grid = 8192 blocks x 256.
// ---------------------------------------------------------------------------
__global__ __launch_bounds__(256) void cvt_cl(const float* __restrict__ src,
                                              __hip_bfloat16* __restrict__ dst) {
    unsigned idx = blockIdx.x * 256 + threadIdx.x;   // 2,097,152 units
    unsigned px  = idx & 4095u;
    unsigned oc8 = (idx >> 12) & 31u;
    unsigned img = idx >> 17;
    const float* s = src + ((long long)(img * 256 + oc8 * 8)) * 4096 + px;
    unsigned short h[8];
#pragma unroll
    for (int j = 0; j < 8; ++j) {
        __hip_bfloat16 v = __float2bfloat16(s[(long long)j * 4096]);
        h[j] = *(unsigned short*)&v;
    }
    uint4 pk;
    pk.x = (unsigned)h[0] | ((unsigned)h[1] << 16);
    pk.y = (unsigned)h[2] | ((unsigned)h[3] << 16);
    pk.z = (unsigned)h[4] | ((unsigned)h[5] << 16);
    pk.w = (unsigned)h[6] | ((unsigned)h[7] << 16);
    *(uint4*)(dst + ((long long)(img * 4096 + px) * 256 + oc8 * 8)) = pk;
}

// ---------------------------------------------------------------------------
// MFMA 3x3 conv (opt. dilated). Xb channels-last bf16; Wtb transformed bf16.
// Block: 64 oc x (ROWS x 64) px; K-loop: 8 chunks of 32 ic, 9 taps each.
// LDS X: [r][c][khi ^ ((c>>1)&3)][8ic] (conflict-free ds_read_b128).
// LDS W: [tap][khi][64 oc][8ic].
// Output D: row=oc (lane>>4)*4+reg, col=px lane&15  [m89 mapping].
// ---------------------------------------------------------------------------
template<int ROWS, int DIL, bool HAS_RES, bool OUT_F32, bool OUT_BF16>
__global__ __launch_bounds__(256) void conv_mfma(
    const __hip_bfloat16* __restrict__ Xb,
    const __hip_bfloat16* __restrict__ Wtb,
    const float* __restrict__ bias,
    const float* __restrict__ res,
    float* __restrict__ outf,
    __hip_bfloat16* __restrict__ outb)
{
    constexpr int RH = ROWS + 2 * DIL;
    constexpr int RW = 64 + 2 * DIL;        // 66 or 68 (even -> bank math holds)
    constexpr int XU = RH * RW * 4;         // 16B units
    constexpr int WU = 9 * 4 * 64;
    __shared__ __align__(16) char smem[XU * 16 + WU * 16];
    char* Xs  = smem;
    char* Wsm = smem + XU * 16;

    const int y0  = blockIdx.x * ROWS;
    const int o0  = blockIdx.y * 64;
    const int img = blockIdx.z;
    const int tid = threadIdx.x;
    const int lane = tid & 63;
    const int wv = tid >> 6;
    constexpr int PXT = (ROWS == 4) ? 4 : 2;
    const int wrow = (ROWS == 4) ? wv : (wv >> 1);
    const int wcol = (ROWS == 4) ? 0 : ((wv & 1) * 32);
    const int l15 = lane & 15, g = lane >> 4;

    f32x4 acc[4][PXT];
#pragma unroll
    for (int a = 0; a < 4; ++a)
#pragma unroll
        for (int t = 0; t < PXT; ++t) { f32x4 z = {0.f,0.f,0.f,0.f}; acc[a][t] = z; }

    const __hip_bfloat16* Ximg = Xb + (long long)img * (4096 * 256);

    for (int c0 = 0; c0 < 256; c0 += 32) {
        // stage X (reg-staged; OOB -> zeros; swizzled khi slot)
        for (int u = tid; u < XU; u += 256) {
            int s  = u & 3;
            int rc = u >> 2;
            int c  = rc % RW, r = rc / RW;
            int khi = s ^ ((c >> 1) & 3);
            int y = y0 + r - DIL, x = c - DIL;
            uint4 vv = make_uint4(0u, 0u, 0u, 0u);
            if ((unsigned)y < 64u && (unsigned)x < 64u)
                vv = *(const uint4*)(Ximg + (((y << 6) + x) * 256 + c0 + khi * 8));
            *(uint4*)(Xs + u * 16) = vv;
        }
        // stage W (fully coalesced)
        const __hip_bfloat16* Wc = Wtb + (long long)(c0 >> 5) * 73728;
        for (int u = tid; u < WU; u += 256) {
            int oc = u & 63, kh = (u >> 6) & 3, tap = u >> 8;
            uint4 vv = *(const uint4*)(Wc + ((long long)((tap * 4 + kh) * 256 + o0 + oc)) * 8);
            *(uint4*)(Wsm + u * 16) = vv;
        }
        __syncthreads();
#pragma unroll
        for (int tap = 0; tap < 9; ++tap) {
            const int dy = tap / 3, dx = tap % 3;
            short8 af[4], bfr[PXT];
#pragma unroll
            for (int a = 0; a < 4; ++a)
                af[a] = *(const short8*)(Wsm + ((tap * 4 + g) * 64 + a * 16 + l15) * 16);
            const int r = wrow + dy * DIL;
#pragma unroll
            for (int t = 0; t < PXT; ++t) {
                int c = wcol + t * 16 + l15 + dx * DIL;
                int s = g ^ ((c >> 1) & 3);
                bfr[t] = *(const short8*)(Xs + ((r * RW + c) * 4 + s) * 16);
            }
#pragma unroll
            for (int a = 0; a < 4; ++a)
#pragma unroll
                for (int t = 0; t < PXT; ++t)
                    acc[a][t] = __builtin_amdgcn_mfma_f32_16x16x32_bf16(
                        af[a], bfr[t], acc[a][t], 0, 0, 0);
        }
        __syncthreads();
    }

    // epilogue: bias + leaky (+ fp32 residual); fp32 chw and/or bf16 hwc out
    const int prow = (y0 + wrow) * 64;
#pragma unroll
    for (int a = 0; a < 4; ++a) {
        const int ocb = o0 + a * 16 + g * 4;
        const float b0 = bias[ocb + 0], b1 = bias[ocb + 1];
        const float b2 = bias[ocb + 2], b3 = bias[ocb + 3];
#pragma unroll
        for (int t = 0; t < PXT; ++t) {
            const int p = prow + wcol + t * 16 + l15;
            float v[4] = { acc[a][t][0] + b0, acc[a][t][1] + b1,
                           acc[a][t][2] + b2, acc[a][t][3] + b3 };
            ushort4 pk;
#pragma unroll
            for (int j = 0; j < 4; ++j) {
                float vv = v[j];
                vv = vv > 0.f ? vv : 0.2f * vv;
                if (HAS_RES) vv += res[(long long)(img * 256 + ocb + j) * 4096 + p];
                if (OUT_F32) outf[(long long)(img * 256 + ocb + j) * 4096 + p] = vv;
                __hip_bfloat16 h = __float2bfloat16(vv);
                ((unsigned short*)&pk)[j] = *(unsigned short*)&h;
            }
            if (OUT_BF16)
                *(ushort4*)(outb + ((long long)(img * 4096 + p) * 256 + ocb)) = pk;
        }
    }
}

// ---------------------------------------------------------------------------
extern "C" void kernel_launch(void* const* d_in, const int* in_sizes, int n_in,
                              void* d_out, int out_size, void* d_ws, size_t ws_size,
                              hipStream_t stream)
{
    if (ws_size < (size_t)NEED_FLOATS * sizeof(float)) return;

    const float* xs  = (const float*)d_in[0];
    const float* Wq  = (const float*)d_in[2];
    const float* bq  = (const float*)d_in[3];
    const float* Wk  = (const float*)d_in[4];
    const float* bk  = (const float*)d_in[5];
    const float* Wv  = (const float*)d_in[6];
    const float* bv  = (const float*)d_in[7];
    const float* Wl  = (const float*)d_in[8];
    const float* bl  = (const float*)d_in[9];
    const float* Wf1 = (const float*)d_in[10];
    const float* bf1 = (const float*)d_in[11];
    const float* Wf2 = (const float*)d_in[12];
    const float* bf2 = (const float*)d_in[13];

    float* ws = (float*)d_ws;
    __hip_bfloat16* wtb0 = (__hip_bfloat16*)(ws + OFF_WTB0);
    __hip_bfloat16* wtb1 = (__hip_bfloat16*)(ws + OFF_WTB1);
    __hip_bfloat16* wtb2 = (__hip_bfloat16*)(ws + OFF_WTB2);
    float* at   = ws + OFF_AT;
    float* scr  = ws + OFF_SCR;
    float* Qp   = scr + SCR_QP;
    float* Kp   = scr + SCR_KP;
    float* Vp   = scr + SCR_VP;
    float* sc   = scr + SCR_SC;
    float* part = scr + SCR_PART;
    float* val  = scr + SCR_VAL;
    __hip_bfloat16* atb  = (__hip_bfloat16*)(scr);             // alias (attn dead)
    __hip_bfloat16* x1b  = (__hip_bfloat16*)(scr + 8388608);
    __hip_bfloat16* ff1b = (__hip_bfloat16*)(scr + 16777216);
    float* x1 = (float*)d_out;   // fp32 x1 lives in d_out

    // 1) conv weight transforms (bf16 MFMA layout)
    transform_w_bf<<<2304, 256, 0, stream>>>(Wl,  wtb0);
    transform_w_bf<<<2304, 256, 0, stream>>>(Wf1, wtb1);
    transform_w_bf<<<2304, 256, 0, stream>>>(Wf2, wtb2);

    // 2) per-scale attention (fp32)
    const int PH[4]  = {32, 16, 8, 4};
    const int LP[4]  = {5, 4, 3, 2};
    const int SPL[4] = {256, 128, 8, 1};
    for (int i = 0; i < 4; ++i) {
        const int ph = PH[i], lp = LP[i];
        const int oh = 64 / ph;
        const int Ntok = 8 * oh * oh;
        const int D = 64 * ph * ph;
        const int off = i * 64;
        const int S = SPL[i];

        dim3 g(32, 3, 16);
        gemm_qkv_patch<<<g, 256, 0, stream>>>(xs, Wq, bq, Wk, bk, Wv, bv,
                                              Qp, Kp, Vp, off, lp, oh, Ntok, D);

        const int nt = (Ntok + 127) / 128;
        float* pbuf = (S == 1) ? sc : part;
        dim3 g1(nt, nt, 2 * S);
        gemm_nt_splitk<<<g1, 256, 0, stream>>>(Qp, Kp, pbuf, Ntok, D, S);

        const long long nn2 = 2LL * Ntok * Ntok;
        const float inv = 1.0f / sqrtf((float)D);
        reduce_scale<<<(int)((nn2 + 255) / 256), 256, 0, stream>>>(pbuf, sc, Ntok, S, inv);

        softmax_rows<<<2 * Ntok, 256, 0, stream>>>(sc, Ntok);

        dim3 g2(D / 128, nt, 2);
        gemm_nn<<<g2, 256, 0, stream>>>(sc, Vp, val, Ntok, D, Ntok,
                                        (long long)Ntok * Ntok,
                                        (long long)Ntok * D,
                                        (long long)Ntok * D);

        unpatchify<<<16384, 256, 0, stream>>>(val, at, off, ph, ph, oh, oh, Ntok, D);
    }

    // 3) atten_res -> channels-last bf16
    cvt_cl<<<8192, 256, 0, stream>>>(at, atb);

    // 4) conv chain (bf16 MFMA, fp32 accum + fp32 residuals)
    {
        dim3 gc(16, 4, 16);   // 4-row strips
        // x1 = xs + leaky(conv(atten)); write fp32 (d_out) + bf16 hwc (x1b)
        conv_mfma<4, 1, true, true, true><<<gc, 256, 0, stream>>>(
            atb, wtb0, bl, xs, x1, x1b);
        // ff1 = leaky(conv(x1)); bf16 hwc only
        conv_mfma<4, 1, false, false, true><<<gc, 256, 0, stream>>>(
            x1b, wtb1, bf1, nullptr, nullptr, ff1b);
    }
    {
        dim3 gc(32, 4, 16);   // 2-row strips (dilated halo)
        // out = x1 + leaky(dconv(ff1)); fp32 to d_out (res == dst, same-thread)
        conv_mfma<2, 2, true, true, false><<<gc, 256, 0, stream>>>(
            ff1b, wtb2, bf2, x1, (float*)d_out, nullptr);
    }
}

// Round 4
// 1279.553 us; speedup vs baseline: 3.4942x; 1.4631x over previous
//
#include <hip/hip_runtime.h>
#include <hip/hip_bf16.h>
#include <math.h>

// ---------------------------------------------------------------------------
// C=256, H=W=64, BT=16, b=2, t=8, scales (32,16,8,4).
// Round 4: attention GEMMs -> bf16 MFMA (scores NT + att@V NT via pre-
// transposed V). Convs already MFMA. QKV GEMM still fp32 (next target).
// Workspace peak = 36,536,320 floats = 139.4 MiB.
// ---------------------------------------------------------------------------
typedef __attribute__((ext_vector_type(8))) short short8;
typedef __attribute__((ext_vector_type(4))) float f32x4;

constexpr long long OFF_WTB0 = 0;
constexpr long long OFF_WTB1 = 294912;
constexpr long long OFF_WTB2 = 589824;
constexpr long long OFF_SCR  = 884736;
constexpr long long SCR_QPB  = 0;          // bf16 Q patch  (2,Ntok,D)
constexpr long long SCR_KPB  = 2097152;
constexpr long long SCR_VTB  = 4194304;    // bf16 V transposed (2,D,Ntok)
constexpr long long SCR_SC   = 6291456;    // fp32 scores
constexpr long long SCR_SCB  = 14680064;   // bf16 probs
constexpr long long SCR_PART = 18874368;   // fp32 split-K partials
constexpr long long SCR_VAL  = 23068672;   // fp32 att@V
constexpr long long SCR_SZ   = 27262976;
constexpr long long OFF_ATB  = OFF_SCR + SCR_SZ;
constexpr long long NEED_FLOATS = OFF_ATB + 8388608;   // 36,536,320

// ---------------------------------------------------------------------------
__global__ void transform_w_bf(const float* __restrict__ W, __hip_bfloat16* __restrict__ Wt) {
    int idx = blockIdx.x * 256 + threadIdx.x;      // 589824
    if (idx >= 589824) return;
    int i    = idx & 7;
    int o    = (idx >> 3) & 255;
    int khi  = (idx >> 11) & 3;
    int tap  = (idx >> 13) % 9;
    int chunk = idx / 73728;
    int c = chunk * 32 + khi * 8 + i;
    Wt[idx] = __float2bfloat16(W[((long long)o * 256 + c) * 9 + tap]);
}

// ---------------------------------------------------------------------------
// Fused QKV slice GEMM (fp32 compute) with bf16 patchified store.
// Q,K -> (b, Ntok, D) bf16;  V -> TRANSPOSED (b, D, Ntok) bf16.
// ---------------------------------------------------------------------------
__global__ __launch_bounds__(256) void gemm_qkv_patch(
    const float* __restrict__ xs,
    const float* __restrict__ Wq, const float* __restrict__ bq,
    const float* __restrict__ Wk, const float* __restrict__ bk,
    const float* __restrict__ Wv, const float* __restrict__ bv,
    unsigned short* __restrict__ Qpb, unsigned short* __restrict__ Kpb,
    unsigned short* __restrict__ Vtb,
    int m0, int lp, int oh, int Ntok, int D)
{
    __shared__ float As[16][68];
    __shared__ float Bs[16][128];
    const int mat = blockIdx.y;
    const float* W  = (mat == 0) ? Wq : (mat == 1) ? Wk : Wv;
    const float* bi = (mat == 0) ? bq : (mat == 1) ? bk : bv;
    const int n0 = blockIdx.x * 128;
    const int n  = blockIdx.z;
    const float* Xn = xs + (long long)n * 1048576;
    const int tid = threadIdx.x;
    const int tx = tid & 15, ty = tid >> 4;
    const int arow = tid >> 2, akc = (tid & 3) * 4;
    const int brow = tid >> 4, bcol = (tid & 15) * 8;

    float acc[4][8];
#pragma unroll
    for (int i = 0; i < 4; ++i) {
        float bv0 = bi[m0 + ty * 4 + i];
#pragma unroll
        for (int j = 0; j < 8; ++j) acc[i][j] = bv0;
    }

    for (int k0 = 0; k0 < 256; k0 += 16) {
        float4 a4 = *(const float4*)(W + (long long)(m0 + arow) * 256 + k0 + akc);
        const float* p = Xn + (long long)(k0 + brow) * 4096 + n0 + bcol;
        float4 b0 = *(const float4*)p;
        float4 b1 = *(const float4*)(p + 4);
        __syncthreads();
        As[akc + 0][arow] = a4.x; As[akc + 1][arow] = a4.y;
        As[akc + 2][arow] = a4.z; As[akc + 3][arow] = a4.w;
        *(float4*)&Bs[brow][bcol]     = b0;
        *(float4*)&Bs[brow][bcol + 4] = b1;
        __syncthreads();
#pragma unroll
        for (int kk = 0; kk < 16; ++kk) {
            float av[4], bvv[8];
            *(float4*)&av[0]  = *(const float4*)&As[kk][ty * 4];
            *(float4*)&bvv[0] = *(const float4*)&Bs[kk][tx * 8];
            *(float4*)&bvv[4] = *(const float4*)&Bs[kk][tx * 8 + 4];
#pragma unroll
            for (int i = 0; i < 4; ++i)
#pragma unroll
                for (int j = 0; j < 8; ++j)
                    acc[i][j] = fmaf(av[i], bvv[j], acc[i][j]);
        }
    }

    const int b2 = n >> 3, tt = n & 7;
    const int pm = (1 << lp) - 1;
    if (mat < 2) {
        unsigned short* out = (mat == 0) ? Qpb : Kpb;
#pragma unroll
        for (int i = 0; i < 4; ++i) {
            int c = ty * 4 + i;
#pragma unroll
            for (int jj = 0; jj < 8; jj += 4) {
                int p0 = n0 + tx * 8 + jj;
                int y = p0 >> 6, x = p0 & 63;
                int m = (tt * oh + (y >> lp)) * oh + (x >> lp);
                int e = ((((c << lp) + (y & pm)) << lp) + (x & pm));
                ushort4 pk;
#pragma unroll
                for (int q = 0; q < 4; ++q) {
                    __hip_bfloat16 h = __float2bfloat16(acc[i][jj + q]);
                    ((unsigned short*)&pk)[q] = *(unsigned short*)&h;
                }
                *(ushort4*)(out + ((long long)(b2 * Ntok + m)) * D + e) = pk;
            }
        }
    } else {
#pragma unroll
        for (int i = 0; i < 4; ++i) {
            int c = ty * 4 + i;
#pragma unroll
            for (int j = 0; j < 8; ++j) {
                int p0 = n0 + tx * 8 + j;
                int y = p0 >> 6, x = p0 & 63;
                int m = (tt * oh + (y >> lp)) * oh + (x >> lp);
                int e = ((((c << lp) + (y & pm)) << lp) + (x & pm));
                __hip_bfloat16 h = __float2bfloat16(acc[i][j]);
                Vtb[((long long)b2 * D + e) * Ntok + m] = *(unsigned short*)&h;
            }
        }
    }
}

// ---------------------------------------------------------------------------
// bf16 MFMA NT GEMM, optional split-K, M/N guards, K zero-pad tail.
// out[(s*2+b)*M*N + i*N + j] = alpha * sum_{k slice s} A[i][k]*B[j][k]
// ---------------------------------------------------------------------------
__global__ __launch_bounds__(256) void gemm_nt_mfma(
    const unsigned short* __restrict__ A, const unsigned short* __restrict__ B,
    float* __restrict__ P, int M, int N, int K, int S, float alpha)
{
    __shared__ __align__(16) char smem[32768];
    char* AsB = smem;
    char* BsB = smem + 16384;
    const int j0 = blockIdx.x * 128, i0 = blockIdx.y * 128;
    const int bz = blockIdx.z;
    const int b = bz / S, s = bz % S;
    const int klen = K / S;
    const long long kbeg = (long long)s * klen;
    const unsigned short* Ab = A + (long long)b * M * K;
    const unsigned short* Bb = B + (long long)b * N * K;
    const int tid = threadIdx.x;
    const int lane = tid & 63, wv = tid >> 6;
    const int wr = wv >> 1, wc = wv & 1;
    const int l15 = lane & 15, g = lane >> 4;

    f32x4 acc[4][4];
#pragma unroll
    for (int a = 0; a < 4; ++a)
#pragma unroll
        for (int t = 0; t < 4; ++t) { f32x4 z = {0.f,0.f,0.f,0.f}; acc[a][t] = z; }

    const int srow = tid >> 3, sslot = tid & 7;
    for (int kc = 0; kc < klen; kc += 64) {
        const long long kk = kbeg + kc + sslot * 8;
        __syncthreads();
#pragma unroll
        for (int it = 0; it < 4; ++it) {
            int row = srow + it * 32;
            int rg = i0 + row, cg = j0 + row;
            uint4 va = make_uint4(0u,0u,0u,0u), vb = va;
            if (rg < M && kk + 8 <= (long long)K)
                va = *(const uint4*)(Ab + (long long)rg * K + kk);
            if (cg < N && kk + 8 <= (long long)K)
                vb = *(const uint4*)(Bb + (long long)cg * K + kk);
            int off = row * 128 + (sslot ^ (row & 7)) * 16;
            *(uint4*)(AsB + off) = va;
            *(uint4*)(BsB + off) = vb;
        }
        __syncthreads();
#pragma unroll
        for (int ks = 0; ks < 2; ++ks) {
            short8 af[4], bfr[4];
#pragma unroll
            for (int a = 0; a < 4; ++a) {
                int r = wr * 64 + a * 16 + l15;
                af[a] = *(const short8*)(AsB + r * 128 + (((ks << 2) + g) ^ (r & 7)) * 16);
            }
#pragma unroll
            for (int t = 0; t < 4; ++t) {
                int r = wc * 64 + t * 16 + l15;
                bfr[t] = *(const short8*)(BsB + r * 128 + (((ks << 2) + g) ^ (r & 7)) * 16);
            }
#pragma unroll
            for (int a = 0; a < 4; ++a)
#pragma unroll
                for (int t = 0; t < 4; ++t)
                    acc[a][t] = __builtin_amdgcn_mfma_f32_16x16x32_bf16(
                        af[a], bfr[t], acc[a][t], 0, 0, 0);
        }
    }

    float* Pb = P + (long long)(s * 2 + b) * M * N;
#pragma unroll
    for (int a = 0; a < 4; ++a) {
        int row0 = i0 + wr * 64 + a * 16 + g * 4;
        if (row0 >= M) continue;
#pragma unroll
        for (int t = 0; t < 4; ++t) {
            int col = j0 + wc * 64 + t * 16 + l15;
            if (col >= N) continue;
#pragma unroll
            for (int r = 0; r < 4; ++r) {
                int row = row0 + r;
                if (row < M) Pb[(long long)row * N + col] = acc[a][t][r] * alpha;
            }
        }
    }
}

__global__ void reduce_scale(const float* __restrict__ P, float* __restrict__ Sc,
                             int Ntok, int S, float inv) {
    long long idx = (long long)blockIdx.x * 256 + threadIdx.x;
    long long tot = 2LL * Ntok * Ntok;
    if (idx >= tot) return;
    float a = 0.f;
    for (int s = 0; s < S; ++s) a += P[(long long)s * tot + idx];
    Sc[idx] = a * inv;
}

__global__ __launch_bounds__(256) void softmax_bf(float* __restrict__ Sc,
                                                  unsigned short* __restrict__ Pb,
                                                  int Ntok) {
    float* p = Sc + (long long)blockIdx.x * Ntok;
    unsigned short* o = Pb + (long long)blockIdx.x * Ntok;
    const int tid = threadIdx.x;
    const int lane = tid & 63, wv = tid >> 6;
    __shared__ float redm[4];
    __shared__ float reds[4];

    float m = -3.402823466e38f;
    for (int j = tid; j < Ntok; j += 256) m = fmaxf(m, p[j]);
#pragma unroll
    for (int off = 1; off < 64; off <<= 1) m = fmaxf(m, __shfl_xor(m, off, 64));
    if (lane == 0) redm[wv] = m;
    __syncthreads();
    m = fmaxf(fmaxf(redm[0], redm[1]), fmaxf(redm[2], redm[3]));

    float sum = 0.f;
    for (int j = tid; j < Ntok; j += 256) {
        float e = expf(p[j] - m);
        p[j] = e;
        sum += e;
    }
#pragma unroll
    for (int off = 1; off < 64; off <<= 1) sum += __shfl_xor(sum, off, 64);
    if (lane == 0) reds[wv] = sum;
    __syncthreads();
    sum = reds[0] + reds[1] + reds[2] + reds[3];
    float inv = 1.f / sum;
    for (int j = tid; j < Ntok; j += 256) {
        __hip_bfloat16 h = __float2bfloat16(p[j] * inv);
        o[j] = *(unsigned short*)&h;
    }
}

// un-patchify: val (b,N,D) fp32 -> atb bf16 channels-last slice.
__global__ void unpatchify_bf(const float* __restrict__ val,
                              unsigned short* __restrict__ atb,
                              int off, int lp, int oh, int Ntok, int D) {
    unsigned idx = blockIdx.x * 256 + threadIdx.x;
    if (idx >= 4194304u) return;
    unsigned c  = idx & 63u;
    unsigned px = (idx >> 6) & 4095u;
    unsigned img = idx >> 18;
    unsigned y = px >> 6, x = px & 63u;
    unsigned b = img >> 3, tt = img & 7u;
    unsigned pm = (1u << lp) - 1u;
    unsigned m = (tt * oh + (y >> lp)) * oh + (x >> lp);
    unsigned e = (((c << lp) + (y & pm)) << lp) + (x & pm);
    float v = val[((long long)b * Ntok + m) * D + e];
    __hip_bfloat16 h = __float2bfloat16(v);
    atb[((long long)img * 4096 + px) * 256 + off + c] = *(unsigned short*)&h;
}

// ---------------------------------------------------------------------------
template<int ROWS, int DIL, bool HAS_RES, bool OUT_F32, bool OUT_BF16>
__global__ __launch_bounds__(256) void conv_mfma(
    const __hip_bfloat16* __restrict__ Xb,
    const __hip_bfloat16* __restrict__ Wtb,
    const float* __restrict__ bias,
    const float* __restrict__ res,
    float* __restrict__ outf,
    __hip_bfloat16* __restrict__ outb)
{
    constexpr int RH = ROWS + 2 * DIL;
    constexpr int RW = 64 + 2 * DIL;
    constexpr int XU = RH * RW * 4;
    constexpr int WU = 9 * 4 * 64;
    __shared__ __align__(16) char smem[XU * 16 + WU * 16];
    char* Xs  = smem;
    char* Wsm = smem + XU * 16;

    const int y0  = blockIdx.x * ROWS;
    const int o0  = blockIdx.y * 64;
    const int img = blockIdx.z;
    const int tid = threadIdx.x;
    const int lane = tid & 63;
    const int wv = tid >> 6;
    constexpr int PXT = (ROWS == 4) ? 4 : 2;
    const int wrow = (ROWS == 4) ? wv : (wv >> 1);
    const int wcol = (ROWS == 4) ? 0 : ((wv & 1) * 32);
    const int l15 = lane & 15, g = lane >> 4;

    f32x4 acc[4][PXT];
#pragma unroll
    for (int a = 0; a < 4; ++a)
#pragma unroll
        for (int t = 0; t < PXT; ++t) { f32x4 z = {0.f,0.f,0.f,0.f}; acc[a][t] = z; }

    const __hip_bfloat16* Ximg = Xb + (long long)img * (4096 * 256);

    for (int c0 = 0; c0 < 256; c0 += 32) {
        for (int u = tid; u < XU; u += 256) {
            int s  = u & 3;
            int rc = u >> 2;
            int c  = rc % RW, r = rc / RW;
            int khi = s ^ ((c >> 1) & 3);
            int y = y0 + r - DIL, x = c - DIL;
            uint4 vv = make_uint4(0u, 0u, 0u, 0u);
            if ((unsigned)y < 64u && (unsigned)x < 64u)
                vv = *(const uint4*)(Ximg + (((y << 6) + x) * 256 + c0 + khi * 8));
            *(uint4*)(Xs + u * 16) = vv;
        }
        const __hip_bfloat16* Wc = Wtb + (long long)(c0 >> 5) * 73728;
        for (int u = tid; u < WU; u += 256) {
            int oc = u & 63, kh = (u >> 6) & 3, tap = u >> 8;
            uint4 vv = *(const uint4*)(Wc + ((long long)((tap * 4 + kh) * 256 + o0 + oc)) * 8);
            *(uint4*)(Wsm + u * 16) = vv;
        }
        __syncthreads();
#pragma unroll
        for (int tap = 0; tap < 9; ++tap) {
            const int dy = tap / 3, dx = tap % 3;
            short8 af[4], bfr[PXT];
#pragma unroll
            for (int a = 0; a < 4; ++a)
                af[a] = *(const short8*)(Wsm + ((tap * 4 + g) * 64 + a * 16 + l15) * 16);
            const int r = wrow + dy * DIL;
#pragma unroll
            for (int t = 0; t < PXT; ++t) {
                int c = wcol + t * 16 + l15 + dx * DIL;
                int s = g ^ ((c >> 1) & 3);
                bfr[t] = *(const short8*)(Xs + ((r * RW + c) * 4 + s) * 16);
            }
#pragma unroll
            for (int a = 0; a < 4; ++a)
#pragma unroll
                for (int t = 0; t < PXT; ++t)
                    acc[a][t] = __builtin_amdgcn_mfma_f32_16x16x32_bf16(
                        af[a], bfr[t], acc[a][t], 0, 0, 0);
        }
        __syncthreads();
    }

    const int prow = (y0 + wrow) * 64;
#pragma unroll
    for (int a = 0; a < 4; ++a) {
        const int ocb = o0 + a * 16 + g * 4;
        const float b0 = bias[ocb + 0], b1 = bias[ocb + 1];
        const float b2 = bias[ocb + 2], b3 = bias[ocb + 3];
#pragma unroll
        for (int t = 0; t < PXT; ++t) {
            const int p = prow + wcol + t * 16 + l15;
            float v[4] = { acc[a][t][0] + b0, acc[a][t][1] + b1,
                           acc[a][t][2] + b2, acc[a][t][3] + b3 };
            ushort4 pk;
#pragma unroll
            for (int j = 0; j < 4; ++j) {
                float vv = v[j];
                vv = vv > 0.f ? vv : 0.2f * vv;
                if (HAS_RES) vv += res[(long long)(img * 256 + ocb + j) * 4096 + p];
                if (OUT_F32) outf[(long long)(img * 256 + ocb + j) * 4096 + p] = vv;
                __hip_bfloat16 h = __float2bfloat16(vv);
                ((unsigned short*)&pk)[j] = *(unsigned short*)&h;
            }
            if (OUT_BF16)
                *(ushort4*)(outb + ((long long)(img * 4096 + p) * 256 + ocb)) = pk;
        }
    }
}

// ---------------------------------------------------------------------------
extern "C" void kernel_launch(void* const* d_in, const int* in_sizes, int n_in,
                              void* d_out, int out_size, void* d_ws, size_t ws_size,
                              hipStream_t stream)
{
    if (ws_size < (size_t)NEED_FLOATS * sizeof(float)) return;

    const float* xs  = (const float*)d_in[0];
    const float* Wq  = (const float*)d_in[2];
    const float* bq  = (const float*)d_in[3];
    const float* Wk  = (const float*)d_in[4];
    const float* bk  = (const float*)d_in[5];
    const float* Wv  = (const float*)d_in[6];
    const float* bv  = (const float*)d_in[7];
    const float* Wl  = (const float*)d_in[8];
    const float* bl  = (const float*)d_in[9];
    const float* Wf1 = (const float*)d_in[10];
    const float* bf1 = (const float*)d_in[11];
    const float* Wf2 = (const float*)d_in[12];
    const float* bf2 = (const float*)d_in[13];

    float* ws = (float*)d_ws;
    __hip_bfloat16* wtb0 = (__hip_bfloat16*)(ws + OFF_WTB0);
    __hip_bfloat16* wtb1 = (__hip_bfloat16*)(ws + OFF_WTB1);
    __hip_bfloat16* wtb2 = (__hip_bfloat16*)(ws + OFF_WTB2);
    float* scr = ws + OFF_SCR;
    unsigned short* Qpb = (unsigned short*)(scr + SCR_QPB);
    unsigned short* Kpb = (unsigned short*)(scr + SCR_KPB);
    unsigned short* Vtb = (unsigned short*)(scr + SCR_VTB);
    float*          sc   = scr + SCR_SC;
    unsigned short* scb  = (unsigned short*)(scr + SCR_SCB);
    float*          part = scr + SCR_PART;
    float*          val  = scr + SCR_VAL;
    unsigned short* atb  = (unsigned short*)(ws + OFF_ATB);
    __hip_bfloat16* x1b  = (__hip_bfloat16*)(scr);
    __hip_bfloat16* ff1b = (__hip_bfloat16*)(scr + 8388608);
    float* x1 = (float*)d_out;

    transform_w_bf<<<2304, 256, 0, stream>>>(Wl,  wtb0);
    transform_w_bf<<<2304, 256, 0, stream>>>(Wf1, wtb1);
    transform_w_bf<<<2304, 256, 0, stream>>>(Wf2, wtb2);

    const int PH[4]  = {32, 16, 8, 4};
    const int LP[4]  = {5, 4, 3, 2};
    const int SPL[4] = {256, 128, 8, 1};
    for (int i = 0; i < 4; ++i) {
        const int lp = LP[i];
        const int oh = 64 / PH[i];
        const int Ntok = 8 * oh * oh;
        const int D = 64 * PH[i] * PH[i];
        const int off = i * 64;
        const int S = SPL[i];
        const float inv = 1.0f / sqrtf((float)D);

        dim3 g(32, 3, 16);
        gemm_qkv_patch<<<g, 256, 0, stream>>>(xs, Wq, bq, Wk, bk, Wv, bv,
                                              Qpb, Kpb, Vtb, off, lp, oh, Ntok, D);

        const int nt = (Ntok + 127) / 128;
        {
            dim3 g1(nt, nt, 2 * S);
            if (S > 1) {
                gemm_nt_mfma<<<g1, 256, 0, stream>>>(Qpb, Kpb, part,
                                                     Ntok, Ntok, D, S, 1.0f);
                const long long nn2 = 2LL * Ntok * Ntok;
                reduce_scale<<<(int)((nn2 + 255) / 256), 256, 0, stream>>>(
                    part, sc, Ntok, S, inv);
            } else {
                gemm_nt_mfma<<<g1, 256, 0, stream>>>(Qpb, Kpb, sc,
                                                     Ntok, Ntok, D, 1, inv);
            }
        }

        softmax_bf<<<2 * Ntok, 256, 0, stream>>>(sc, scb, Ntok);

        {
            dim3 g2((D + 127) / 128, nt, 2);
            gemm_nt_mfma<<<g2, 256, 0, stream>>>(scb, Vtb, val,
                                                 Ntok, D, Ntok, 1, 1.0f);
        }

        unpatchify_bf<<<16384, 256, 0, stream>>>(val, atb, off, lp, oh, Ntok, D);
    }

    {
        dim3 gc(16, 4, 16);
        conv_mfma<4, 1, true, true, true><<<gc, 256, 0, stream>>>(
            (const __hip_bfloat16*)atb, wtb0, bl, xs, x1, x1b);
        conv_mfma<4, 1, false, false, true><<<gc, 256, 0, stream>>>(
            x1b, wtb1, bf1, nullptr, nullptr, ff1b);
    }
    {
        dim3 gc(32, 4, 16);
        conv_mfma<2, 2, true, true, false><<<gc, 256, 0, stream>>>(
            ff1b, wtb2, bf2, x1, (float*)d_out, nullptr);
    }
}